// Round 6
// baseline (270.884 us; speedup 1.0000x reference)
//
#include <hip/hip_runtime.h>

#define F 128
#define RELS 8
#define KMAX 64
#define NT 32  // nodes per block in fused kernel

typedef __attribute__((ext_vector_type(8))) short short8;
typedef __attribute__((ext_vector_type(4))) float floatx4;

__device__ __forceinline__ unsigned short f2bf(float f) {
    unsigned int u = __float_as_uint(f);
    unsigned int r = (u + 0x7fffu + ((u >> 16) & 1u)) >> 16;
    return (unsigned short)r;
}

// ---------- convert X [N][128] fp32 -> X2 [kc=fi/32][n][32] bf16 ----------
__global__ void cvtX_kernel(const float* __restrict__ X, unsigned short* __restrict__ X2, int N) {
    int t = blockIdx.x * blockDim.x + threadIdx.x;
    if (t >= N * (F / 8)) return;
    int n = t >> 4;
    int q = t & 15;
    int fi = q * 8;
    const float* xp = X + (size_t)n * F + fi;
    float4 v0 = *reinterpret_cast<const float4*>(xp);
    float4 v1 = *reinterpret_cast<const float4*>(xp + 4);
    int kc = fi >> 5;
    int ko = fi & 31;
    short8 o;
    o[0] = (short)f2bf(v0.x); o[1] = (short)f2bf(v0.y);
    o[2] = (short)f2bf(v0.z); o[3] = (short)f2bf(v0.w);
    o[4] = (short)f2bf(v1.x); o[5] = (short)f2bf(v1.y);
    o[6] = (short)f2bf(v1.z); o[7] = (short)f2bf(v1.w);
    *reinterpret_cast<short8*>(X2 + ((size_t)(kc * N + n)) * 32 + ko) = o;
}

// ---------- convert W [R][128][128] fp32 -> W2 [r][kc][fo][32] bf16 (canonical) ----------
__global__ void cvtW_kernel(const float* __restrict__ W, unsigned short* __restrict__ W2) {
    int t = blockIdx.x * blockDim.x + threadIdx.x;
    if (t >= RELS * F * (F / 8)) return;
    int r = t >> 11;
    int rem = t & 2047;
    int fo = rem >> 4;
    int q = rem & 15;
    int fi = q * 8;
    const float* wp = W + ((size_t)r * F + fo) * F + fi;
    float4 v0 = *reinterpret_cast<const float4*>(wp);
    float4 v1 = *reinterpret_cast<const float4*>(wp + 4);
    int kc = fi >> 5;
    int ko = fi & 31;
    short8 o;
    o[0] = (short)f2bf(v0.x); o[1] = (short)f2bf(v0.y);
    o[2] = (short)f2bf(v0.z); o[3] = (short)f2bf(v0.w);
    o[4] = (short)f2bf(v1.x); o[5] = (short)f2bf(v1.y);
    o[6] = (short)f2bf(v1.z); o[7] = (short)f2bf(v1.w);
    *reinterpret_cast<short8*>(W2 + ((size_t)((r * 4 + kc) * F + fo)) * 32 + ko) = o;
}

// ---------- padded-CSR fill: counts[] doubles as fill cursor ----------
__global__ void fillp_kernel(const int* __restrict__ src, const int* __restrict__ dst,
                             const int* __restrict__ et, int* __restrict__ counts,
                             unsigned int* __restrict__ packed, int E) {
    int t = blockIdx.x * blockDim.x + threadIdx.x;
    if (t >= E) return;
    int d = dst[t];
    int slot = atomicAdd(&counts[d], 1);
    if (slot < KMAX)
        packed[(size_t)d * KMAX + slot] = (unsigned int)src[t] | ((unsigned int)et[t] << 24);
}

// ---------- fused aggregate (per-rel X-sums) + transform (MFMA) ----------
// Phase 1: wave w owns nodes nl = w*8..w*8+7; per node, per-rel fp32 sums of X2
//          rows (lane l holds feature elems f0=(l>>4)*32+2*(l&15), f0+1), then
//          bf16-pack to LDS Z[r][nl][128] with XOR swizzle on k-bytes.
// Phase 2: Y_tile(32n x 128) = sum_r Z[r] @ W2[r]^T via mfma 16x16x32;
//          wave w computes col-tiles ct = {2w, 2w+1}.
#define LOF(v) __uint_as_float((v) << 16)
#define HIF(v) __uint_as_float((v) & 0xffff0000u)
#define ACC(rr, vv)                                                        \
    {                                                                      \
        unsigned int _r = (rr);                                            \
        unsigned int _v = (vv);                                            \
        switch (_r) {                                                      \
            case 0: a0x += LOF(_v); a0y += HIF(_v); break;                 \
            case 1: a1x += LOF(_v); a1y += HIF(_v); break;                 \
            case 2: a2x += LOF(_v); a2y += HIF(_v); break;                 \
            case 3: a3x += LOF(_v); a3y += HIF(_v); break;                 \
            case 4: a4x += LOF(_v); a4y += HIF(_v); break;                 \
            case 5: a5x += LOF(_v); a5y += HIF(_v); break;                 \
            case 6: a6x += LOF(_v); a6y += HIF(_v); break;                 \
            default: a7x += LOF(_v); a7y += HIF(_v); break;                \
        }                                                                  \
    }

__global__ __launch_bounds__(256) void fused_kernel(const unsigned int* __restrict__ X2u,
                                                    const unsigned short* __restrict__ W2,
                                                    const int* __restrict__ counts,
                                                    const unsigned int* __restrict__ packed,
                                                    float* __restrict__ Y, int N) {
    __shared__ unsigned int Zl[RELS * NT * 64];  // 64 KB: [r][nl][64 uints = 128 bf16]
    int lane = threadIdx.x & 63;
    int wave = threadIdx.x >> 6;
    int nodebase = blockIdx.x * NT;
    int lpart = (lane >> 4) * N * 16 + (lane & 15);  // uint index of this lane's elem-pair in X2 row

    // ---- phase 1 ----
#pragma unroll 1
    for (int i = 0; i < NT / 4; i++) {
        int nl = wave * (NT / 4) + i;
        int node = nodebase + nl;
        float a0x = 0, a0y = 0, a1x = 0, a1y = 0, a2x = 0, a2y = 0, a3x = 0, a3y = 0;
        float a4x = 0, a4y = 0, a5x = 0, a5y = 0, a6x = 0, a6y = 0, a7x = 0, a7y = 0;
        if (node < N) {
            int cnt = counts[node];
            if (cnt > KMAX) cnt = KMAX;
            const unsigned int* pk = packed + (size_t)node * KMAX;
            int e = 0;
            for (; e + 4 <= cnt; e += 4) {
                uint4 p = *reinterpret_cast<const uint4*>(pk + e);
                unsigned int v0 = X2u[lpart + (int)(p.x & 0xffffffu) * 16];
                unsigned int v1 = X2u[lpart + (int)(p.y & 0xffffffu) * 16];
                unsigned int v2 = X2u[lpart + (int)(p.z & 0xffffffu) * 16];
                unsigned int v3 = X2u[lpart + (int)(p.w & 0xffffffu) * 16];
                ACC(p.x >> 24, v0);
                ACC(p.y >> 24, v1);
                ACC(p.z >> 24, v2);
                ACC(p.w >> 24, v3);
            }
            for (; e < cnt; e++) {
                unsigned int p = pk[e];
                unsigned int v = X2u[lpart + (int)(p & 0xffffffu) * 16];
                ACC(p >> 24, v);
            }
        }
        int sl = lane ^ ((nl & 7) << 2);  // XOR-swizzle uint slot (byte bits 4-6)
        Zl[(0 * NT + nl) * 64 + sl] = (unsigned int)f2bf(a0x) | ((unsigned int)f2bf(a0y) << 16);
        Zl[(1 * NT + nl) * 64 + sl] = (unsigned int)f2bf(a1x) | ((unsigned int)f2bf(a1y) << 16);
        Zl[(2 * NT + nl) * 64 + sl] = (unsigned int)f2bf(a2x) | ((unsigned int)f2bf(a2y) << 16);
        Zl[(3 * NT + nl) * 64 + sl] = (unsigned int)f2bf(a3x) | ((unsigned int)f2bf(a3y) << 16);
        Zl[(4 * NT + nl) * 64 + sl] = (unsigned int)f2bf(a4x) | ((unsigned int)f2bf(a4y) << 16);
        Zl[(5 * NT + nl) * 64 + sl] = (unsigned int)f2bf(a5x) | ((unsigned int)f2bf(a5y) << 16);
        Zl[(6 * NT + nl) * 64 + sl] = (unsigned int)f2bf(a6x) | ((unsigned int)f2bf(a6y) << 16);
        Zl[(7 * NT + nl) * 64 + sl] = (unsigned int)f2bf(a7x) | ((unsigned int)f2bf(a7y) << 16);
    }
    __syncthreads();

    // ---- phase 2 ----
    int lr = lane & 15;
    int lk8 = (lane >> 4) * 8;  // k-elem offset within 32-chunk
    int nl0 = lr;               // A rows for rt=0
    int nl1 = 16 + lr;          // A rows for rt=1
    floatx4 acc00 = {0, 0, 0, 0}, acc01 = {0, 0, 0, 0}, acc10 = {0, 0, 0, 0}, acc11 = {0, 0, 0, 0};
#pragma unroll
    for (int r = 0; r < RELS; r++) {
#pragma unroll
        for (int kc = 0; kc < 4; kc++) {
            int ks = kc * 16 + (lane >> 4) * 4;  // base uint slot of this lane's A-frag
            short8 av0 = *reinterpret_cast<const short8*>(&Zl[(r * NT + nl0) * 64 + (ks ^ ((nl0 & 7) << 2))]);
            short8 av1 = *reinterpret_cast<const short8*>(&Zl[(r * NT + nl1) * 64 + (ks ^ ((nl1 & 7) << 2))]);
            short8 b0 = *reinterpret_cast<const short8*>(W2 + ((size_t)((r * 4 + kc) * F + (wave * 2) * 16 + lr)) * 32 + lk8);
            short8 b1 = *reinterpret_cast<const short8*>(W2 + ((size_t)((r * 4 + kc) * F + (wave * 2 + 1) * 16 + lr)) * 32 + lk8);
            acc00 = __builtin_amdgcn_mfma_f32_16x16x32_bf16(av0, b0, acc00, 0, 0, 0);
            acc01 = __builtin_amdgcn_mfma_f32_16x16x32_bf16(av0, b1, acc01, 0, 0, 0);
            acc10 = __builtin_amdgcn_mfma_f32_16x16x32_bf16(av1, b0, acc10, 0, 0, 0);
            acc11 = __builtin_amdgcn_mfma_f32_16x16x32_bf16(av1, b1, acc11, 0, 0, 0);
        }
    }

    // ---- epilogue: C/D layout col=lane&15, row=(lane>>4)*4+g ----
    int c0 = (wave * 2) * 16 + lr;
    int c1 = (wave * 2 + 1) * 16 + lr;
#pragma unroll
    for (int g = 0; g < 4; g++) {
        int row0 = nodebase + (lane >> 4) * 4 + g;
        if (row0 < N) {
            Y[(size_t)row0 * F + c0] = acc00[g];
            Y[(size_t)row0 * F + c1] = acc01[g];
        }
        int row1 = nodebase + 16 + (lane >> 4) * 4 + g;
        if (row1 < N) {
            Y[(size_t)row1 * F + c0] = acc10[g];
            Y[(size_t)row1 * F + c1] = acc11[g];
        }
    }
}

// ---------- fallback: fused per-edge fp32 GEMV (used only if ws too small) ----------
__global__ void fused_fb_kernel(const float* __restrict__ X, const float* __restrict__ W,
                                const int* __restrict__ src, const int* __restrict__ dst,
                                const int* __restrict__ et, float* __restrict__ Y, int E) {
    int lane = threadIdx.x & 63;
    int wid = (blockIdx.x * blockDim.x + threadIdx.x) >> 6;
    int nw = (gridDim.x * blockDim.x) >> 6;
    for (int e = wid; e < E; e += nw) {
        int s = src[e];
        int d = dst[e];
        int r = et[e];
        const float4* xr = reinterpret_cast<const float4*>(X + (size_t)s * F);
#pragma unroll
        for (int h = 0; h < 2; h++) {
            int fo = lane + (h << 6);
            const float4* wr = reinterpret_cast<const float4*>(W + ((size_t)r * F + fo) * F);
            float acc = 0.f;
#pragma unroll
            for (int i = 0; i < 32; i++) {
                float4 x = xr[i];
                float4 w = wr[i];
                acc += x.x * w.x + x.y * w.y + x.z * w.z + x.w * w.w;
            }
            unsafeAtomicAdd(&Y[(size_t)d * F + fo], acc);
        }
    }
}

extern "C" void kernel_launch(void* const* d_in, const int* in_sizes, int n_in,
                              void* d_out, int out_size, void* d_ws, size_t ws_size,
                              hipStream_t stream) {
    const float* X = (const float*)d_in[0];
    const float* W = (const float*)d_in[1];
    const int* src = (const int*)d_in[2];
    const int* dst = (const int*)d_in[3];
    const int* et  = (const int*)d_in[4];
    int N = in_sizes[0] / F;
    int E = in_sizes[2];
    float* Y = (float*)d_out;

    size_t x2bytes  = (size_t)N * F * 2;
    size_t w2bytes  = (size_t)RELS * F * F * 2;
    size_t cntbytes = ((size_t)N * 4 + 255) & ~255ull;
    size_t pkbytes  = (size_t)N * KMAX * 4;
    size_t need = x2bytes + w2bytes + cntbytes + pkbytes;

    if (ws_size < need) {
        hipMemsetAsync(d_out, 0, (size_t)N * F * sizeof(float), stream);
        fused_fb_kernel<<<2048, 256, 0, stream>>>(X, W, src, dst, et, Y, E);
        return;
    }

    char* ws = (char*)d_ws;
    unsigned short* X2 = (unsigned short*)ws;  ws += x2bytes;
    unsigned short* W2 = (unsigned short*)ws;  ws += w2bytes;
    int* counts        = (int*)ws;             ws += cntbytes;
    unsigned int* packed = (unsigned int*)ws;

    // padded CSR build
    hipMemsetAsync(counts, 0, (size_t)N * 4, stream);
    fillp_kernel<<<(E + 255) / 256, 256, 0, stream>>>(src, dst, et, counts, packed, E);

    // bf16 repack
    cvtX_kernel<<<(N * (F / 8) + 255) / 256, 256, 0, stream>>>(X, X2, N);
    cvtW_kernel<<<(RELS * F * (F / 8) + 255) / 256, 256, 0, stream>>>(W, W2);

    // fused aggregate + transform
    fused_kernel<<<(N + NT - 1) / NT, 256, 0, stream>>>((const unsigned int*)X2, W2, counts, packed, Y, N);
}

// Round 7
// 220.093 us; speedup vs baseline: 1.2308x; 1.2308x over previous
//
#include <hip/hip_runtime.h>

#define F 128
#define RELS 8
#define KMAX 64
#define NT 16  // nodes per block in fused kernel (32KB LDS -> 4 blocks/CU)

typedef __attribute__((ext_vector_type(8))) short short8;
typedef __attribute__((ext_vector_type(4))) float floatx4;

__device__ __forceinline__ unsigned short f2bf(float f) {
    unsigned int u = __float_as_uint(f);
    unsigned int r = (u + 0x7fffu + ((u >> 16) & 1u)) >> 16;
    return (unsigned short)r;
}

// ---------- convert X [N][128] fp32 -> X2 [N][128] bf16 (plain rows) ----------
__global__ void cvtX_kernel(const float* __restrict__ X, unsigned short* __restrict__ X2, int N) {
    int t = blockIdx.x * blockDim.x + threadIdx.x;
    if (t >= N * (F / 8)) return;
    int n = t >> 4;
    int q = t & 15;
    int fi = q * 8;
    const float* xp = X + (size_t)n * F + fi;
    float4 v0 = *reinterpret_cast<const float4*>(xp);
    float4 v1 = *reinterpret_cast<const float4*>(xp + 4);
    short8 o;
    o[0] = (short)f2bf(v0.x); o[1] = (short)f2bf(v0.y);
    o[2] = (short)f2bf(v0.z); o[3] = (short)f2bf(v0.w);
    o[4] = (short)f2bf(v1.x); o[5] = (short)f2bf(v1.y);
    o[6] = (short)f2bf(v1.z); o[7] = (short)f2bf(v1.w);
    *reinterpret_cast<short8*>(X2 + (size_t)n * F + fi) = o;
}

// ---------- convert W [R][128][128] fp32 -> W2 [r][kc][fo][32] bf16 (canonical) ----------
__global__ void cvtW_kernel(const float* __restrict__ W, unsigned short* __restrict__ W2) {
    int t = blockIdx.x * blockDim.x + threadIdx.x;
    if (t >= RELS * F * (F / 8)) return;
    int r = t >> 11;
    int rem = t & 2047;
    int fo = rem >> 4;
    int q = rem & 15;
    int fi = q * 8;
    const float* wp = W + ((size_t)r * F + fo) * F + fi;
    float4 v0 = *reinterpret_cast<const float4*>(wp);
    float4 v1 = *reinterpret_cast<const float4*>(wp + 4);
    int kc = fi >> 5;
    int ko = fi & 31;
    short8 o;
    o[0] = (short)f2bf(v0.x); o[1] = (short)f2bf(v0.y);
    o[2] = (short)f2bf(v0.z); o[3] = (short)f2bf(v0.w);
    o[4] = (short)f2bf(v1.x); o[5] = (short)f2bf(v1.y);
    o[6] = (short)f2bf(v1.z); o[7] = (short)f2bf(v1.w);
    *reinterpret_cast<short8*>(W2 + ((size_t)((r * 4 + kc) * F + fo)) * 32 + ko) = o;
}

// ---------- padded-CSR fill: counts[] doubles as fill cursor ----------
__global__ void fillp_kernel(const int* __restrict__ src, const int* __restrict__ dst,
                             const int* __restrict__ et, int* __restrict__ counts,
                             unsigned int* __restrict__ packed, int E) {
    int t = blockIdx.x * blockDim.x + threadIdx.x;
    if (t >= E) return;
    int d = dst[t];
    int slot = atomicAdd(&counts[d], 1);
    if (slot < KMAX)
        packed[(size_t)d * KMAX + slot] = (unsigned int)src[t] | ((unsigned int)et[t] << 24);
}

// ---------- fused aggregate (per-rel X-sums) + transform (MFMA) ----------
// Phase 1: wave w owns nodes nl = w*4..w*4+3; per node, per-rel fp32 sums of X2
//          rows (lane l holds feature pair 2l,2l+1 -> one coalesced 256B read
//          per edge), bf16-pack to LDS Z[r][nl][128] with XOR swizzle.
// Phase 2: Y_tile(16n x 128) = sum_r Z[r] @ W2[r]^T via mfma 16x16x32;
//          wave w computes col-tiles {2w, 2w+1}.
#define LOF(v) __uint_as_float((v) << 16)
#define HIF(v) __uint_as_float((v) & 0xffff0000u)
#define ACC(rr, vv)                                                        \
    {                                                                      \
        unsigned int _r = (rr);                                            \
        unsigned int _v = (vv);                                            \
        switch (_r) {                                                      \
            case 0: a0x += LOF(_v); a0y += HIF(_v); break;                 \
            case 1: a1x += LOF(_v); a1y += HIF(_v); break;                 \
            case 2: a2x += LOF(_v); a2y += HIF(_v); break;                 \
            case 3: a3x += LOF(_v); a3y += HIF(_v); break;                 \
            case 4: a4x += LOF(_v); a4y += HIF(_v); break;                 \
            case 5: a5x += LOF(_v); a5y += HIF(_v); break;                 \
            case 6: a6x += LOF(_v); a6y += HIF(_v); break;                 \
            default: a7x += LOF(_v); a7y += HIF(_v); break;                \
        }                                                                  \
    }

__global__ __launch_bounds__(256) void fused_kernel(const unsigned int* __restrict__ X2u,
                                                    const unsigned short* __restrict__ W2,
                                                    const int* __restrict__ counts,
                                                    const unsigned int* __restrict__ packed,
                                                    float* __restrict__ Y, int N) {
    __shared__ unsigned int Zl[RELS * NT * 64];  // 32 KB: [r][nl][64 uints = 128 bf16]
    int lane = threadIdx.x & 63;
    int wave = threadIdx.x >> 6;
    int nodebase = blockIdx.x * NT;

    // ---- phase 1 ----
#pragma unroll 1
    for (int i = 0; i < NT / 4; i++) {
        int nl = wave * (NT / 4) + i;
        int node = nodebase + nl;
        float a0x = 0, a0y = 0, a1x = 0, a1y = 0, a2x = 0, a2y = 0, a3x = 0, a3y = 0;
        float a4x = 0, a4y = 0, a5x = 0, a5y = 0, a6x = 0, a6y = 0, a7x = 0, a7y = 0;
        if (node < N) {
            int cnt = counts[node];
            if (cnt > KMAX) cnt = KMAX;
            const unsigned int* pk = packed + (size_t)node * KMAX;
            int nq = cnt >> 2;
            int rem = cnt & 3;
            if (nq) {
                // software-pipelined quad loop: next index-quad loads under current gathers
                uint4 p = *reinterpret_cast<const uint4*>(pk);
#pragma unroll 1
                for (int qi = 1; qi < nq; qi++) {
                    uint4 pn = *reinterpret_cast<const uint4*>(pk + qi * 4);
                    unsigned int v0 = X2u[(size_t)(p.x & 0xffffffu) * 64 + lane];
                    unsigned int v1 = X2u[(size_t)(p.y & 0xffffffu) * 64 + lane];
                    unsigned int v2 = X2u[(size_t)(p.z & 0xffffffu) * 64 + lane];
                    unsigned int v3 = X2u[(size_t)(p.w & 0xffffffu) * 64 + lane];
                    ACC(p.x >> 24, v0);
                    ACC(p.y >> 24, v1);
                    ACC(p.z >> 24, v2);
                    ACC(p.w >> 24, v3);
                    p = pn;
                }
                unsigned int v0 = X2u[(size_t)(p.x & 0xffffffu) * 64 + lane];
                unsigned int v1 = X2u[(size_t)(p.y & 0xffffffu) * 64 + lane];
                unsigned int v2 = X2u[(size_t)(p.z & 0xffffffu) * 64 + lane];
                unsigned int v3 = X2u[(size_t)(p.w & 0xffffffu) * 64 + lane];
                ACC(p.x >> 24, v0);
                ACC(p.y >> 24, v1);
                ACC(p.z >> 24, v2);
                ACC(p.w >> 24, v3);
            }
            const unsigned int* tail = pk + nq * 4;
            for (int t = 0; t < rem; t++) {
                unsigned int p = tail[t];
                unsigned int v = X2u[(size_t)(p & 0xffffffu) * 64 + lane];
                ACC(p >> 24, v);
            }
        }
        int sl = lane ^ ((nl & 7) << 2);  // XOR-swizzle uint slot
        Zl[(0 * NT + nl) * 64 + sl] = (unsigned int)f2bf(a0x) | ((unsigned int)f2bf(a0y) << 16);
        Zl[(1 * NT + nl) * 64 + sl] = (unsigned int)f2bf(a1x) | ((unsigned int)f2bf(a1y) << 16);
        Zl[(2 * NT + nl) * 64 + sl] = (unsigned int)f2bf(a2x) | ((unsigned int)f2bf(a2y) << 16);
        Zl[(3 * NT + nl) * 64 + sl] = (unsigned int)f2bf(a3x) | ((unsigned int)f2bf(a3y) << 16);
        Zl[(4 * NT + nl) * 64 + sl] = (unsigned int)f2bf(a4x) | ((unsigned int)f2bf(a4y) << 16);
        Zl[(5 * NT + nl) * 64 + sl] = (unsigned int)f2bf(a5x) | ((unsigned int)f2bf(a5y) << 16);
        Zl[(6 * NT + nl) * 64 + sl] = (unsigned int)f2bf(a6x) | ((unsigned int)f2bf(a6y) << 16);
        Zl[(7 * NT + nl) * 64 + sl] = (unsigned int)f2bf(a7x) | ((unsigned int)f2bf(a7y) << 16);
    }
    __syncthreads();

    // ---- phase 2: one 16-row tile, wave w does col-tiles {2w, 2w+1} ----
    int lr = lane & 15;
    int hi = lane >> 4;
    int lk8 = hi * 8;
    int nl0 = lr;
    floatx4 acc00 = {0, 0, 0, 0}, acc01 = {0, 0, 0, 0};
#pragma unroll
    for (int r = 0; r < RELS; r++) {
#pragma unroll
        for (int kc = 0; kc < 4; kc++) {
            int ks = kc * 16 + hi * 4;
            short8 av = *reinterpret_cast<const short8*>(&Zl[(r * NT + nl0) * 64 + (ks ^ ((nl0 & 7) << 2))]);
            short8 b0 = *reinterpret_cast<const short8*>(W2 + ((size_t)((r * 4 + kc) * F + (wave * 2) * 16 + lr)) * 32 + lk8);
            short8 b1 = *reinterpret_cast<const short8*>(W2 + ((size_t)((r * 4 + kc) * F + (wave * 2 + 1) * 16 + lr)) * 32 + lk8);
            acc00 = __builtin_amdgcn_mfma_f32_16x16x32_bf16(av, b0, acc00, 0, 0, 0);
            acc01 = __builtin_amdgcn_mfma_f32_16x16x32_bf16(av, b1, acc01, 0, 0, 0);
        }
    }

    // ---- epilogue: C/D layout col=lane&15, row=(lane>>4)*4+g ----
    int c0 = (wave * 2) * 16 + lr;
    int c1 = (wave * 2 + 1) * 16 + lr;
#pragma unroll
    for (int g = 0; g < 4; g++) {
        int row = nodebase + hi * 4 + g;
        if (row < N) {
            Y[(size_t)row * F + c0] = acc00[g];
            Y[(size_t)row * F + c1] = acc01[g];
        }
    }
}

// ---------- fallback: fused per-edge fp32 GEMV (used only if ws too small) ----------
__global__ void fused_fb_kernel(const float* __restrict__ X, const float* __restrict__ W,
                                const int* __restrict__ src, const int* __restrict__ dst,
                                const int* __restrict__ et, float* __restrict__ Y, int E) {
    int lane = threadIdx.x & 63;
    int wid = (blockIdx.x * blockDim.x + threadIdx.x) >> 6;
    int nw = (gridDim.x * blockDim.x) >> 6;
    for (int e = wid; e < E; e += nw) {
        int s = src[e];
        int d = dst[e];
        int r = et[e];
        const float4* xr = reinterpret_cast<const float4*>(X + (size_t)s * F);
#pragma unroll
        for (int h = 0; h < 2; h++) {
            int fo = lane + (h << 6);
            const float4* wr = reinterpret_cast<const float4*>(W + ((size_t)r * F + fo) * F);
            float acc = 0.f;
#pragma unroll
            for (int i = 0; i < 32; i++) {
                float4 x = xr[i];
                float4 w = wr[i];
                acc += x.x * w.x + x.y * w.y + x.z * w.z + x.w * w.w;
            }
            unsafeAtomicAdd(&Y[(size_t)d * F + fo], acc);
        }
    }
}

extern "C" void kernel_launch(void* const* d_in, const int* in_sizes, int n_in,
                              void* d_out, int out_size, void* d_ws, size_t ws_size,
                              hipStream_t stream) {
    const float* X = (const float*)d_in[0];
    const float* W = (const float*)d_in[1];
    const int* src = (const int*)d_in[2];
    const int* dst = (const int*)d_in[3];
    const int* et  = (const int*)d_in[4];
    int N = in_sizes[0] / F;
    int E = in_sizes[2];
    float* Y = (float*)d_out;

    size_t x2bytes  = (size_t)N * F * 2;
    size_t w2bytes  = (size_t)RELS * F * F * 2;
    size_t cntbytes = ((size_t)N * 4 + 255) & ~255ull;
    size_t pkbytes  = (size_t)N * KMAX * 4;
    size_t need = x2bytes + w2bytes + cntbytes + pkbytes;

    if (ws_size < need) {
        hipMemsetAsync(d_out, 0, (size_t)N * F * sizeof(float), stream);
        fused_fb_kernel<<<2048, 256, 0, stream>>>(X, W, src, dst, et, Y, E);
        return;
    }

    char* ws = (char*)d_ws;
    unsigned short* X2 = (unsigned short*)ws;  ws += x2bytes;
    unsigned short* W2 = (unsigned short*)ws;  ws += w2bytes;
    int* counts        = (int*)ws;             ws += cntbytes;
    unsigned int* packed = (unsigned int*)ws;

    // padded CSR build
    hipMemsetAsync(counts, 0, (size_t)N * 4, stream);
    fillp_kernel<<<(E + 255) / 256, 256, 0, stream>>>(src, dst, et, counts, packed, E);

    // bf16 repack
    cvtX_kernel<<<(N * (F / 8) + 255) / 256, 256, 0, stream>>>(X, X2, N);
    cvtW_kernel<<<(RELS * F * (F / 8) + 255) / 256, 256, 0, stream>>>(W, W2);

    // fused aggregate + transform
    fused_kernel<<<(N + NT - 1) / NT, 256, 0, stream>>>((const unsigned int*)X2, W2, counts, packed, Y, N);
}